// Round 6
// baseline (223.289 us; speedup 1.0000x reference)
//
#include <hip/hip_runtime.h>
#include <hip/hip_bf16.h>
#include <stdint.h>

#define B_SZ 1024
#define N_SZ 65536
#define M_SZ 128

typedef short bf16x8 __attribute__((ext_vector_type(8)));
typedef short bf16x4 __attribute__((ext_vector_type(4)));
typedef float f32x4 __attribute__((ext_vector_type(4)));

__device__ __forceinline__ unsigned short f2bf(float f) {
    uint32_t u = __float_as_uint(f);
    uint32_t r = (u + 0x7FFFu + ((u >> 16) & 1u)) >> 16;  // RNE
    return (unsigned short)r;
}

// ---- kernel 0 (fused): blocks 0..255 transpose E||D -> EDt[c][b] bf16; 256..383 zero out.
__global__ __launch_bounds__(256) void k_edt(const float* __restrict__ E,
                                             const float* __restrict__ D,
                                             unsigned short* __restrict__ EDt,
                                             float* __restrict__ out) {
    if (blockIdx.x >= 256) {
        int i = (blockIdx.x - 256) * 1024 + threadIdx.x * 4;
        *(float4*)(out + i) = (float4){0.f, 0.f, 0.f, 0.f};
        return;
    }
    __shared__ float tile[32][33];
    int bx = blockIdx.x & 31;
    int cy = blockIdx.x >> 5;
    int b0 = bx * 32, c0 = cy * 32;
    const float* src = (c0 < M_SZ) ? E : D;
    int cs0 = c0 & (M_SZ - 1);
    int t = threadIdx.x;
    int i = t >> 3, j = (t & 7) * 4;
    const float* p = src + (size_t)(b0 + i) * M_SZ + cs0 + j;
    float4 v = *(const float4*)p;
    tile[i][j] = v.x; tile[i][j + 1] = v.y; tile[i][j + 2] = v.z; tile[i][j + 3] = v.w;
    __syncthreads();
    int c = t >> 3, b4 = (t & 7) * 4;
    unsigned short* q = EDt + (size_t)(c0 + c) * B_SZ + b0 + b4;
    ushort4 o;
    o.x = f2bf(tile[b4 + 0][c]); o.y = f2bf(tile[b4 + 1][c]);
    o.z = f2bf(tile[b4 + 2][c]); o.w = f2bf(tile[b4 + 3][c]);
    *(ushort4*)q = o;
}

// =======================  PASS 1  =======================
// NCt[m][n] = C[n][m]*(1-W) + V,  (W|V) = A^T @ (E||D)
// block: 128 n x 256 c, K=1024 in 32-chunks. A staged via LDS (double-buffered,
// R3-proven [32][132] layout); ED fragments read DIRECT from global (EDt is
// 512 KB, L2-resident; frag = 16B contiguous per lane).
#define AS_LD 132

__global__ __launch_bounds__(256, 2) void k_pass1(
    const float* __restrict__ A,            // [B][N]
    const unsigned short* __restrict__ EDt, // [256][B] bf16
    const float* __restrict__ C,            // [N][M]
    unsigned short* __restrict__ NCt)       // [M][N] bf16 out (transposed)
{
    __shared__ __align__(16) unsigned short As[2][32 * AS_LD];
    const int t = threadIdx.x;
    const int lane = t & 63;
    const int wv = t >> 6;
    const int wvn = wv >> 1, wvc = wv & 1;
    const int g = lane >> 4;
    const int m16 = lane & 15;
    const int n0 = blockIdx.x * 128;

    const int kb = t >> 3;          // A staging: b-row within chunk 0..31
    const int cA = (t & 7) * 16;    // A staging: n-col start

    int cb[8];
#pragma unroll
    for (int fj = 0; fj < 4; ++fj) { cb[fj] = wvc * 4 + fj; cb[fj + 4] = 8 + wvc * 4 + fj; }

    // ED fragment base pointers (k-contiguous; imm offsets cover all chunks? bk*2B up to 2KB
    // exceeds 13-bit? 1024*2=2048 < 4096 OK) — one base per fj.
    const unsigned short* edP[8];
#pragma unroll
    for (int fj = 0; fj < 8; ++fj)
        edP[fj] = EDt + (size_t)(cb[fj] * 16 + m16) * B_SZ + g * 8;

    f32x4 acc[4][8];
#pragma unroll
    for (int i = 0; i < 4; ++i)
#pragma unroll
        for (int j = 0; j < 8; ++j) acc[i][j] = (f32x4){0.f, 0.f, 0.f, 0.f};

    // ---- prologue: stage A chunk 0 into buf 0
    {
        const float* p = A + (size_t)kb * N_SZ + n0 + cA;
        float4 a0 = ((const float4*)p)[0], a1 = ((const float4*)p)[1];
        float4 a2 = ((const float4*)p)[2], a3 = ((const float4*)p)[3];
        ushort4* w = (ushort4*)&As[0][kb * AS_LD + cA];
        ushort4 o;
        o.x = f2bf(a0.x); o.y = f2bf(a0.y); o.z = f2bf(a0.z); o.w = f2bf(a0.w); w[0] = o;
        o.x = f2bf(a1.x); o.y = f2bf(a1.y); o.z = f2bf(a1.z); o.w = f2bf(a1.w); w[1] = o;
        o.x = f2bf(a2.x); o.y = f2bf(a2.y); o.z = f2bf(a2.z); o.w = f2bf(a2.w); w[2] = o;
        o.x = f2bf(a3.x); o.y = f2bf(a3.y); o.z = f2bf(a3.z); o.w = f2bf(a3.w); w[3] = o;
    }
    __syncthreads();

    int cur = 0;
    for (int bk = 0; bk < B_SZ; bk += 32) {
        const bool last = (bk + 32 >= B_SZ);
        const int nk = last ? 0 : bk + 32;

        // (1) prefetch next A chunk -> regs
        const float* p = A + (size_t)(nk + kb) * N_SZ + n0 + cA;
        float4 a0 = ((const float4*)p)[0], a1 = ((const float4*)p)[1];
        float4 a2 = ((const float4*)p)[2], a3 = ((const float4*)p)[3];

        // (2) fragments: A from LDS buf[cur], ED direct from global (L2-hot)
        bf16x8 af[4];
#pragma unroll
        for (int fi = 0; fi < 4; ++fi) {
            int nl = wvn * 64 + fi * 16 + m16;
#pragma unroll
            for (int j = 0; j < 8; ++j)
                af[fi][j] = (short)As[cur][(g * 8 + j) * AS_LD + nl];
        }
        bf16x8 bfr[8];
#pragma unroll
        for (int fj = 0; fj < 8; ++fj)
            bfr[fj] = *(const bf16x8*)(edP[fj] + bk);

        // (3) MFMAs
#pragma unroll
        for (int fj = 0; fj < 8; ++fj)
#pragma unroll
            for (int fi = 0; fi < 4; ++fi)
                acc[fi][fj] = __builtin_amdgcn_mfma_f32_16x16x32_bf16(af[fi], bfr[fj], acc[fi][fj], 0, 0, 0);

        // (4) convert + write next A buffer
        if (!last) {
            const int nxt = cur ^ 1;
            ushort4* w = (ushort4*)&As[nxt][kb * AS_LD + cA];
            ushort4 o;
            o.x = f2bf(a0.x); o.y = f2bf(a0.y); o.z = f2bf(a0.z); o.w = f2bf(a0.w); w[0] = o;
            o.x = f2bf(a1.x); o.y = f2bf(a1.y); o.z = f2bf(a1.z); o.w = f2bf(a1.w); w[1] = o;
            o.x = f2bf(a2.x); o.y = f2bf(a2.y); o.z = f2bf(a2.z); o.w = f2bf(a2.w); w[2] = o;
            o.x = f2bf(a3.x); o.y = f2bf(a3.y); o.z = f2bf(a3.z); o.w = f2bf(a3.w); w[3] = o;
        }
        __syncthreads();
        cur ^= 1;
    }

    // epilogue: D layout col=lane&15, row=(lane>>4)*4+r. NCt[m][n]: n contiguous per lane.
#pragma unroll
    for (int fi = 0; fi < 4; ++fi)
#pragma unroll
        for (int fj = 0; fj < 4; ++fj) {
            int n_base = n0 + wvn * 64 + fi * 16 + g * 4;
            int m = wvc * 64 + fj * 16 + m16;
            bf16x4 o;
#pragma unroll
            for (int r = 0; r < 4; ++r) {
                float w = acc[fi][fj][r];
                float v = acc[fi][fj + 4][r];
                float cc = C[(size_t)(n_base + r) * M_SZ + m];
                o[r] = (short)f2bf(cc * (1.0f - w) + v);
            }
            *(bf16x4*)&NCt[(size_t)m * N_SZ + n_base] = o;
        }
}

// =======================  PASS 2  =======================
// out[b][m] += A[b][k] * NCt[m][k]; block = 128b x 128m, 64 K-splits x 1024.
// FULLY LDS-FREE: both operands are k-contiguous in global -> direct fragment
// loads (A: 2x float4 + convert; NCt: one 16B bf16x8). No barriers.
// Reg ping-pong depth-2: compute slot s, then load chunk c+2 into s.
__global__ __launch_bounds__(256, 2) void k_pass2(
    const float* __restrict__ A,
    const unsigned short* __restrict__ NCt,  // [M][N]
    float* __restrict__ out)
{
    const int t = threadIdx.x;
    const int lane = t & 63;
    const int wv = t >> 6;
    const int wvb = wv >> 1, wvm = wv & 1;
    const int g = lane >> 4;
    const int m16 = lane & 15;
    // XCD grouping: blocks sharing a k0 (bid stride 64 -> bid%8 const) -> same XCD L2
    const int k0 = (blockIdx.x & 63) << 10;
    const int b0 = (blockIdx.x >> 6) << 7;

    const float* aP[4];
    const unsigned short* nP[4];
#pragma unroll
    for (int fi = 0; fi < 4; ++fi)
        aP[fi] = A + (size_t)(b0 + wvb * 64 + fi * 16 + m16) * N_SZ + k0 + g * 8;
#pragma unroll
    for (int fj = 0; fj < 4; ++fj)
        nP[fj] = NCt + (size_t)(wvm * 64 + fj * 16 + m16) * N_SZ + k0 + g * 8;

    f32x4 acc[4][4];
#pragma unroll
    for (int i = 0; i < 4; ++i)
#pragma unroll
        for (int j = 0; j < 4; ++j) acc[i][j] = (f32x4){0.f, 0.f, 0.f, 0.f};

    float4 ra[2][4][2];  // [slot][fi][q]
    bf16x8 rb[2][4];     // [slot][fj]

    // prologue: load chunks 0 -> slot0, 1 -> slot1
#pragma unroll
    for (int s = 0; s < 2; ++s) {
#pragma unroll
        for (int fi = 0; fi < 4; ++fi) {
            ra[s][fi][0] = ((const float4*)(aP[fi] + s * 32))[0];
            ra[s][fi][1] = ((const float4*)(aP[fi] + s * 32))[1];
        }
#pragma unroll
        for (int fj = 0; fj < 4; ++fj)
            rb[s][fj] = *(const bf16x8*)(nP[fj] + s * 32);
    }

#pragma unroll 2
    for (int c = 0; c < 32; ++c) {
        const int s = c & 1;
        // compute chunk c from slot s
        bf16x8 af[4];
#pragma unroll
        for (int fi = 0; fi < 4; ++fi) {
            af[fi][0] = (short)f2bf(ra[s][fi][0].x); af[fi][1] = (short)f2bf(ra[s][fi][0].y);
            af[fi][2] = (short)f2bf(ra[s][fi][0].z); af[fi][3] = (short)f2bf(ra[s][fi][0].w);
            af[fi][4] = (short)f2bf(ra[s][fi][1].x); af[fi][5] = (short)f2bf(ra[s][fi][1].y);
            af[fi][6] = (short)f2bf(ra[s][fi][1].z); af[fi][7] = (short)f2bf(ra[s][fi][1].w);
        }
#pragma unroll
        for (int fi = 0; fi < 4; ++fi)
#pragma unroll
            for (int fj = 0; fj < 4; ++fj)
                acc[fi][fj] = __builtin_amdgcn_mfma_f32_16x16x32_bf16(af[fi], rb[s][fj], acc[fi][fj], 0, 0, 0);

        // load chunk c+2 into slot s (registers now free)
        if (c + 2 < 32) {
            const int off = (c + 2) * 32;
#pragma unroll
            for (int fi = 0; fi < 4; ++fi) {
                ra[s][fi][0] = ((const float4*)(aP[fi] + off))[0];
                ra[s][fi][1] = ((const float4*)(aP[fi] + off))[1];
            }
#pragma unroll
            for (int fj = 0; fj < 4; ++fj)
                rb[s][fj] = *(const bf16x8*)(nP[fj] + off);
        }
    }

#pragma unroll
    for (int fi = 0; fi < 4; ++fi)
#pragma unroll
        for (int fj = 0; fj < 4; ++fj)
#pragma unroll
            for (int r = 0; r < 4; ++r) {
                int b = b0 + wvb * 64 + fi * 16 + g * 4 + r;
                int m = wvm * 64 + fj * 16 + m16;
                atomicAdd(out + (size_t)b * M_SZ + m, acc[fi][fj][r]);
            }
}

extern "C" void kernel_launch(void* const* d_in, const int* in_sizes, int n_in,
                              void* d_out, int out_size, void* d_ws, size_t ws_size,
                              hipStream_t stream) {
    const float* A  = (const float*)d_in[0];   // address [B,N]
    const float* E  = (const float*)d_in[1];   // erase   [B,M]
    const float* Dd = (const float*)d_in[2];   // add     [B,M]
    const float* C  = (const float*)d_in[3];   // content [N,M]
    float* out = (float*)d_out;

    unsigned short* NCt = (unsigned short*)d_ws;                                     // 16 MB [M][N]
    unsigned short* EDt = (unsigned short*)((char*)d_ws + (size_t)M_SZ * N_SZ * 2);  // +512 KB

    k_edt <<<384, 256, 0, stream>>>(E, Dd, EDt, out);
    k_pass1<<<512, 256, 0, stream>>>(A, EDt, C, NCt);
    k_pass2<<<512, 256, 0, stream>>>(A, NCt, out);
}

// Round 7
// 182.395 us; speedup vs baseline: 1.2242x; 1.2242x over previous
//
#include <hip/hip_runtime.h>
#include <hip/hip_bf16.h>
#include <stdint.h>

#define B_SZ 1024
#define N_SZ 65536
#define M_SZ 128

typedef short bf16x8 __attribute__((ext_vector_type(8)));
typedef short bf16x4 __attribute__((ext_vector_type(4)));
typedef float f32x4 __attribute__((ext_vector_type(4)));

__device__ __forceinline__ unsigned short f2bf(float f) {
    uint32_t u = __float_as_uint(f);
    uint32_t r = (u + 0x7FFFu + ((u >> 16) & 1u)) >> 16;  // RNE
    return (unsigned short)r;
}

// ---- kernel 0 (fused): blocks 0..255 transpose E||D -> EDt[c][b] bf16; 256..383 zero out.
__global__ __launch_bounds__(256) void k_edt(const float* __restrict__ E,
                                             const float* __restrict__ D,
                                             unsigned short* __restrict__ EDt,
                                             float* __restrict__ out) {
    if (blockIdx.x >= 256) {
        int i = (blockIdx.x - 256) * 1024 + threadIdx.x * 4;
        *(float4*)(out + i) = (float4){0.f, 0.f, 0.f, 0.f};
        return;
    }
    __shared__ float tile[32][33];
    int bx = blockIdx.x & 31;
    int cy = blockIdx.x >> 5;
    int b0 = bx * 32, c0 = cy * 32;
    const float* src = (c0 < M_SZ) ? E : D;
    int cs0 = c0 & (M_SZ - 1);
    int t = threadIdx.x;
    int i = t >> 3, j = (t & 7) * 4;
    const float* p = src + (size_t)(b0 + i) * M_SZ + cs0 + j;
    float4 v = *(const float4*)p;
    tile[i][j] = v.x; tile[i][j + 1] = v.y; tile[i][j + 2] = v.z; tile[i][j + 3] = v.w;
    __syncthreads();
    int c = t >> 3, b4 = (t & 7) * 4;
    unsigned short* q = EDt + (size_t)(c0 + c) * B_SZ + b0 + b4;
    ushort4 o;
    o.x = f2bf(tile[b4 + 0][c]); o.y = f2bf(tile[b4 + 1][c]);
    o.z = f2bf(tile[b4 + 2][c]); o.w = f2bf(tile[b4 + 3][c]);
    *(ushort4*)q = o;
}

// =======================  PASS 1  (verbatim R3 — proven 175.8 component) =======
// NCt[m][n] = C[n][m]*(1-W) + V,  (W|V) = A^T @ (E||D)
// block: 128 n x 256 c, K=1024 in 32-chunks, double-buffered reg-staged.
// As: [32 k][132] bf16 (pad-132: scalar frag reads 2-way alias = free).
// EDs: [256 c][40] bf16, k-contiguous rows.
#define AS_LD 132
#define ED_LD 40

__global__ __launch_bounds__(256, 2) void k_pass1(
    const float* __restrict__ A,            // [B][N]
    const unsigned short* __restrict__ EDt, // [256][B] bf16
    const float* __restrict__ C,            // [N][M]
    unsigned short* __restrict__ NCt)       // [M][N] bf16 out (transposed)
{
    __shared__ __align__(16) unsigned short As[2][32 * AS_LD];
    __shared__ __align__(16) unsigned short EDs[2][256 * ED_LD];
    const int t = threadIdx.x;
    const int lane = t & 63;
    const int wv = t >> 6;
    const int wvn = wv >> 1, wvc = wv & 1;
    const int g = lane >> 4;
    const int m16 = lane & 15;
    const int n0 = blockIdx.x * 128;

    const int kb = t >> 3;          // A: b-row within chunk 0..31
    const int cA = (t & 7) * 16;    // A: n-col start
    const int colq = t >> 3;        // ED col 0..31 (+32*p8)
    const int seg = t & 7;          // ED 4-short segment

    int cb[8];
#pragma unroll
    for (int fj = 0; fj < 4; ++fj) { cb[fj] = wvc * 4 + fj; cb[fj + 4] = 8 + wvc * 4 + fj; }

    f32x4 acc[4][8];
#pragma unroll
    for (int i = 0; i < 4; ++i)
#pragma unroll
        for (int j = 0; j < 8; ++j) acc[i][j] = (f32x4){0.f, 0.f, 0.f, 0.f};

    // ---- prologue: stage chunk 0 into buf 0
    {
        const float* p = A + (size_t)kb * N_SZ + n0 + cA;
        float4 a0 = ((const float4*)p)[0], a1 = ((const float4*)p)[1];
        float4 a2 = ((const float4*)p)[2], a3 = ((const float4*)p)[3];
        ushort4* w = (ushort4*)&As[0][kb * AS_LD + cA];
        ushort4 o;
        o.x = f2bf(a0.x); o.y = f2bf(a0.y); o.z = f2bf(a0.z); o.w = f2bf(a0.w); w[0] = o;
        o.x = f2bf(a1.x); o.y = f2bf(a1.y); o.z = f2bf(a1.z); o.w = f2bf(a1.w); w[1] = o;
        o.x = f2bf(a2.x); o.y = f2bf(a2.y); o.z = f2bf(a2.z); o.w = f2bf(a2.w); w[2] = o;
        o.x = f2bf(a3.x); o.y = f2bf(a3.y); o.z = f2bf(a3.z); o.w = f2bf(a3.w); w[3] = o;
#pragma unroll
        for (int p8 = 0; p8 < 8; ++p8) {
            int col = p8 * 32 + colq;
            ushort4 v = *(const ushort4*)(EDt + (size_t)col * B_SZ + seg * 4);
            *(ushort4*)&EDs[0][col * ED_LD + seg * 4] = v;
        }
    }
    __syncthreads();

    int cur = 0;
    for (int bk = 0; bk < B_SZ; bk += 32) {
        const bool last = (bk + 32 >= B_SZ);
        const int nk = last ? 0 : bk + 32;

        // (1) prefetch next chunk -> regs
        const float* p = A + (size_t)(nk + kb) * N_SZ + n0 + cA;
        float4 a0 = ((const float4*)p)[0], a1 = ((const float4*)p)[1];
        float4 a2 = ((const float4*)p)[2], a3 = ((const float4*)p)[3];
        ushort4 e[8];
#pragma unroll
        for (int p8 = 0; p8 < 8; ++p8) {
            int col = p8 * 32 + colq;
            e[p8] = *(const ushort4*)(EDt + (size_t)col * B_SZ + nk + seg * 4);
        }

        // (2) fragment reads from buf[cur]
        bf16x8 af[4];
#pragma unroll
        for (int fi = 0; fi < 4; ++fi) {
            int nl = wvn * 64 + fi * 16 + m16;
#pragma unroll
            for (int j = 0; j < 8; ++j)
                af[fi][j] = (short)As[cur][(g * 8 + j) * AS_LD + nl];
        }
        bf16x8 bfr[8];
#pragma unroll
        for (int fj = 0; fj < 8; ++fj)
            bfr[fj] = *(const bf16x8*)&EDs[cur][(cb[fj] * 16 + m16) * ED_LD + g * 8];

        // (3) MFMAs
#pragma unroll
        for (int fj = 0; fj < 8; ++fj)
#pragma unroll
            for (int fi = 0; fi < 4; ++fi)
                acc[fi][fj] = __builtin_amdgcn_mfma_f32_16x16x32_bf16(af[fi], bfr[fj], acc[fi][fj], 0, 0, 0);

        // (4) convert + write next buffer
        if (!last) {
            const int nxt = cur ^ 1;
            ushort4* w = (ushort4*)&As[nxt][kb * AS_LD + cA];
            ushort4 o;
            o.x = f2bf(a0.x); o.y = f2bf(a0.y); o.z = f2bf(a0.z); o.w = f2bf(a0.w); w[0] = o;
            o.x = f2bf(a1.x); o.y = f2bf(a1.y); o.z = f2bf(a1.z); o.w = f2bf(a1.w); w[1] = o;
            o.x = f2bf(a2.x); o.y = f2bf(a2.y); o.z = f2bf(a2.z); o.w = f2bf(a2.w); w[2] = o;
            o.x = f2bf(a3.x); o.y = f2bf(a3.y); o.z = f2bf(a3.z); o.w = f2bf(a3.w); w[3] = o;
#pragma unroll
            for (int p8 = 0; p8 < 8; ++p8) {
                int col = p8 * 32 + colq;
                *(ushort4*)&EDs[nxt][col * ED_LD + seg * 4] = e[p8];
            }
        }
        __syncthreads();
        cur ^= 1;
    }

    // epilogue: D layout col=lane&15, row=(lane>>4)*4+r. NCt[m][n]: n contiguous per lane.
#pragma unroll
    for (int fi = 0; fi < 4; ++fi)
#pragma unroll
        for (int fj = 0; fj < 4; ++fj) {
            int n_base = n0 + wvn * 64 + fi * 16 + g * 4;
            int m = wvc * 64 + fj * 16 + m16;
            bf16x4 o;
#pragma unroll
            for (int r = 0; r < 4; ++r) {
                float w = acc[fi][fj][r];
                float v = acc[fi][fj + 4][r];
                float cc = C[(size_t)(n_base + r) * M_SZ + m];
                o[r] = (short)f2bf(cc * (1.0f - w) + v);
            }
            *(bf16x4*)&NCt[(size_t)m * N_SZ + n_base] = o;
        }
}

// =======================  PASS 2  =======================
// out[b][m] += A[b][k] * NCt[m][k]; block = 128b x 128m.
// R3 body (depth-1, LDS-staged, proven) — geometry change only:
// 128 k-splits x 512 k -> grid 1024 = 3 blocks/CU (TLP latency hiding).
// XCD grouping: same-k0 blocks are stride-128 -> same bid%8 -> same XCD L2
// shares the NCt [128][512] slice.
#define L2_LD 40
#define KCH 512

__global__ __launch_bounds__(256, 3) void k_pass2(
    const float* __restrict__ A,
    const unsigned short* __restrict__ NCt,  // [M][N]
    float* __restrict__ out)
{
    __shared__ __align__(16) unsigned short As2[2][128 * L2_LD];
    __shared__ __align__(16) unsigned short NCs[2][128 * L2_LD];
    const int t = threadIdx.x;
    const int lane = t & 63;
    const int wv = t >> 6;
    const int wvb = wv >> 1, wvm = wv & 1;
    const int g = lane >> 4;
    const int m16 = lane & 15;
    const int k0 = (blockIdx.x & 127) << 9;   // 128 k-splits of 512
    const int b0 = (blockIdx.x >> 7) << 7;    // 8 b-groups of 128

    const int row = t >> 1, half = t & 1;  // staging: row 0..127, 16-k half

    f32x4 acc[4][4];
#pragma unroll
    for (int i = 0; i < 4; ++i)
#pragma unroll
        for (int j = 0; j < 4; ++j) acc[i][j] = (f32x4){0.f, 0.f, 0.f, 0.f};

    // prologue: stage chunk 0 -> buf 0
    {
        const float* p = A + (size_t)(b0 + row) * N_SZ + k0 + half * 16;
        float4 a0 = ((const float4*)p)[0], a1 = ((const float4*)p)[1];
        float4 a2 = ((const float4*)p)[2], a3 = ((const float4*)p)[3];
        ushort4* w = (ushort4*)&As2[0][row * L2_LD + half * 16];
        ushort4 o;
        o.x = f2bf(a0.x); o.y = f2bf(a0.y); o.z = f2bf(a0.z); o.w = f2bf(a0.w); w[0] = o;
        o.x = f2bf(a1.x); o.y = f2bf(a1.y); o.z = f2bf(a1.z); o.w = f2bf(a1.w); w[1] = o;
        o.x = f2bf(a2.x); o.y = f2bf(a2.y); o.z = f2bf(a2.z); o.w = f2bf(a2.w); w[2] = o;
        o.x = f2bf(a3.x); o.y = f2bf(a3.y); o.z = f2bf(a3.z); o.w = f2bf(a3.w); w[3] = o;
        const uint4* pn = (const uint4*)(NCt + (size_t)row * N_SZ + k0 + half * 16);
        uint4 n0v = pn[0], n1v = pn[1];
        uint4* wn = (uint4*)&NCs[0][row * L2_LD + half * 16];
        wn[0] = n0v; wn[1] = n1v;
    }
    __syncthreads();

    int cur = 0;
    for (int kk = 0; kk < KCH; kk += 32) {
        const bool last = (kk + 32 >= KCH);
        const int nkk = last ? 0 : kk + 32;

        // prefetch
        const float* p = A + (size_t)(b0 + row) * N_SZ + k0 + nkk + half * 16;
        float4 a0 = ((const float4*)p)[0], a1 = ((const float4*)p)[1];
        float4 a2 = ((const float4*)p)[2], a3 = ((const float4*)p)[3];
        const uint4* pn = (const uint4*)(NCt + (size_t)row * N_SZ + k0 + nkk + half * 16);
        uint4 n0v = pn[0], n1v = pn[1];

        // fragment reads (all linear b128)
        bf16x8 af[4];
#pragma unroll
        for (int fi = 0; fi < 4; ++fi)
            af[fi] = *(const bf16x8*)&As2[cur][(wvb * 64 + fi * 16 + m16) * L2_LD + g * 8];
        bf16x8 bfr[4];
#pragma unroll
        for (int fj = 0; fj < 4; ++fj)
            bfr[fj] = *(const bf16x8*)&NCs[cur][(wvm * 64 + fj * 16 + m16) * L2_LD + g * 8];

#pragma unroll
        for (int fi = 0; fi < 4; ++fi)
#pragma unroll
            for (int fj = 0; fj < 4; ++fj)
                acc[fi][fj] = __builtin_amdgcn_mfma_f32_16x16x32_bf16(af[fi], bfr[fj], acc[fi][fj], 0, 0, 0);

        if (!last) {
            const int nxt = cur ^ 1;
            ushort4* w = (ushort4*)&As2[nxt][row * L2_LD + half * 16];
            ushort4 o;
            o.x = f2bf(a0.x); o.y = f2bf(a0.y); o.z = f2bf(a0.z); o.w = f2bf(a0.w); w[0] = o;
            o.x = f2bf(a1.x); o.y = f2bf(a1.y); o.z = f2bf(a1.z); o.w = f2bf(a1.w); w[1] = o;
            o.x = f2bf(a2.x); o.y = f2bf(a2.y); o.z = f2bf(a2.z); o.w = f2bf(a2.w); w[2] = o;
            o.x = f2bf(a3.x); o.y = f2bf(a3.y); o.z = f2bf(a3.z); o.w = f2bf(a3.w); w[3] = o;
            uint4* wn = (uint4*)&NCs[nxt][row * L2_LD + half * 16];
            wn[0] = n0v; wn[1] = n1v;
        }
        __syncthreads();
        cur ^= 1;
    }

#pragma unroll
    for (int fi = 0; fi < 4; ++fi)
#pragma unroll
        for (int fj = 0; fj < 4; ++fj)
#pragma unroll
            for (int r = 0; r < 4; ++r) {
                int b = b0 + wvb * 64 + fi * 16 + g * 4 + r;
                int m = wvm * 64 + fj * 16 + m16;
                atomicAdd(out + (size_t)b * M_SZ + m, acc[fi][fj][r]);
            }
}

extern "C" void kernel_launch(void* const* d_in, const int* in_sizes, int n_in,
                              void* d_out, int out_size, void* d_ws, size_t ws_size,
                              hipStream_t stream) {
    const float* A  = (const float*)d_in[0];   // address [B,N]
    const float* E  = (const float*)d_in[1];   // erase   [B,M]
    const float* Dd = (const float*)d_in[2];   // add     [B,M]
    const float* C  = (const float*)d_in[3];   // content [N,M]
    float* out = (float*)d_out;

    unsigned short* NCt = (unsigned short*)d_ws;                                     // 16 MB [M][N]
    unsigned short* EDt = (unsigned short*)((char*)d_ws + (size_t)M_SZ * N_SZ * 2);  // +512 KB

    k_edt <<<384, 256, 0, stream>>>(E, Dd, EDt, out);
    k_pass1<<<512, 256, 0, stream>>>(A, EDt, C, NCt);
    k_pass2<<<1024, 256, 0, stream>>>(A, NCt, out);
}

// Round 9
// 166.863 us; speedup vs baseline: 1.3382x; 1.0931x over previous
//
#include <hip/hip_runtime.h>
#include <hip/hip_bf16.h>
#include <stdint.h>

#define B_SZ 1024
#define N_SZ 65536
#define M_SZ 128

typedef short bf16x8 __attribute__((ext_vector_type(8)));
typedef short bf16x4 __attribute__((ext_vector_type(4)));
typedef float f32x4 __attribute__((ext_vector_type(4)));

__device__ __forceinline__ unsigned short f2bf(float f) {
    uint32_t u = __float_as_uint(f);
    uint32_t r = (u + 0x7FFFu + ((u >> 16) & 1u)) >> 16;  // RNE
    return (unsigned short)r;
}

// ---- kernel 0: EDt[c][b] bf16, c<128 -> E[b][c], else D[b][c-128]. [256][1024]
__global__ __launch_bounds__(256) void k_edt(const float* __restrict__ E,
                                             const float* __restrict__ D,
                                             unsigned short* __restrict__ EDt) {
    __shared__ float tile[32][33];
    int bx = blockIdx.x & 31;
    int cy = blockIdx.x >> 5;
    int b0 = bx * 32, c0 = cy * 32;
    const float* src = (c0 < M_SZ) ? E : D;
    int cs0 = c0 & (M_SZ - 1);
    int t = threadIdx.x;
    int i = t >> 3, j = (t & 7) * 4;
    const float* p = src + (size_t)(b0 + i) * M_SZ + cs0 + j;
    float4 v = *(const float4*)p;
    tile[i][j] = v.x; tile[i][j + 1] = v.y; tile[i][j + 2] = v.z; tile[i][j + 3] = v.w;
    __syncthreads();
    int c = t >> 3, b4 = (t & 7) * 4;
    unsigned short* q = EDt + (size_t)(c0 + c) * B_SZ + b0 + b4;
    ushort4 o;
    o.x = f2bf(tile[b4 + 0][c]); o.y = f2bf(tile[b4 + 1][c]);
    o.z = f2bf(tile[b4 + 2][c]); o.w = f2bf(tile[b4 + 3][c]);
    *(ushort4*)q = o;
}

// =======================  PASS 1  (verbatim R3 — proven) =======================
// NCt[m][n] = C[n][m]*(1-W) + V,  (W|V) = A^T @ (E||D)
#define AS_LD 132
#define ED_LD 40

__global__ __launch_bounds__(256, 2) void k_pass1(
    const float* __restrict__ A,            // [B][N]
    const unsigned short* __restrict__ EDt, // [256][B] bf16
    const float* __restrict__ C,            // [N][M]
    unsigned short* __restrict__ NCt)       // [M][N] bf16 out (transposed)
{
    __shared__ __align__(16) unsigned short As[2][32 * AS_LD];
    __shared__ __align__(16) unsigned short EDs[2][256 * ED_LD];
    const int t = threadIdx.x;
    const int lane = t & 63;
    const int wv = t >> 6;
    const int wvn = wv >> 1, wvc = wv & 1;
    const int g = lane >> 4;
    const int m16 = lane & 15;
    const int n0 = blockIdx.x * 128;

    const int kb = t >> 3;
    const int cA = (t & 7) * 16;
    const int colq = t >> 3;
    const int seg = t & 7;

    int cb[8];
#pragma unroll
    for (int fj = 0; fj < 4; ++fj) { cb[fj] = wvc * 4 + fj; cb[fj + 4] = 8 + wvc * 4 + fj; }

    f32x4 acc[4][8];
#pragma unroll
    for (int i = 0; i < 4; ++i)
#pragma unroll
        for (int j = 0; j < 8; ++j) acc[i][j] = (f32x4){0.f, 0.f, 0.f, 0.f};

    {
        const float* p = A + (size_t)kb * N_SZ + n0 + cA;
        float4 a0 = ((const float4*)p)[0], a1 = ((const float4*)p)[1];
        float4 a2 = ((const float4*)p)[2], a3 = ((const float4*)p)[3];
        ushort4* w = (ushort4*)&As[0][kb * AS_LD + cA];
        ushort4 o;
        o.x = f2bf(a0.x); o.y = f2bf(a0.y); o.z = f2bf(a0.z); o.w = f2bf(a0.w); w[0] = o;
        o.x = f2bf(a1.x); o.y = f2bf(a1.y); o.z = f2bf(a1.z); o.w = f2bf(a1.w); w[1] = o;
        o.x = f2bf(a2.x); o.y = f2bf(a2.y); o.z = f2bf(a2.z); o.w = f2bf(a2.w); w[2] = o;
        o.x = f2bf(a3.x); o.y = f2bf(a3.y); o.z = f2bf(a3.z); o.w = f2bf(a3.w); w[3] = o;
#pragma unroll
        for (int p8 = 0; p8 < 8; ++p8) {
            int col = p8 * 32 + colq;
            ushort4 v = *(const ushort4*)(EDt + (size_t)col * B_SZ + seg * 4);
            *(ushort4*)&EDs[0][col * ED_LD + seg * 4] = v;
        }
    }
    __syncthreads();

    int cur = 0;
    for (int bk = 0; bk < B_SZ; bk += 32) {
        const bool last = (bk + 32 >= B_SZ);
        const int nk = last ? 0 : bk + 32;

        const float* p = A + (size_t)(nk + kb) * N_SZ + n0 + cA;
        float4 a0 = ((const float4*)p)[0], a1 = ((const float4*)p)[1];
        float4 a2 = ((const float4*)p)[2], a3 = ((const float4*)p)[3];
        ushort4 e[8];
#pragma unroll
        for (int p8 = 0; p8 < 8; ++p8) {
            int col = p8 * 32 + colq;
            e[p8] = *(const ushort4*)(EDt + (size_t)col * B_SZ + nk + seg * 4);
        }

        bf16x8 af[4];
#pragma unroll
        for (int fi = 0; fi < 4; ++fi) {
            int nl = wvn * 64 + fi * 16 + m16;
#pragma unroll
            for (int j = 0; j < 8; ++j)
                af[fi][j] = (short)As[cur][(g * 8 + j) * AS_LD + nl];
        }
        bf16x8 bfr[8];
#pragma unroll
        for (int fj = 0; fj < 8; ++fj)
            bfr[fj] = *(const bf16x8*)&EDs[cur][(cb[fj] * 16 + m16) * ED_LD + g * 8];

#pragma unroll
        for (int fj = 0; fj < 8; ++fj)
#pragma unroll
            for (int fi = 0; fi < 4; ++fi)
                acc[fi][fj] = __builtin_amdgcn_mfma_f32_16x16x32_bf16(af[fi], bfr[fj], acc[fi][fj], 0, 0, 0);

        if (!last) {
            const int nxt = cur ^ 1;
            ushort4* w = (ushort4*)&As[nxt][kb * AS_LD + cA];
            ushort4 o;
            o.x = f2bf(a0.x); o.y = f2bf(a0.y); o.z = f2bf(a0.z); o.w = f2bf(a0.w); w[0] = o;
            o.x = f2bf(a1.x); o.y = f2bf(a1.y); o.z = f2bf(a1.z); o.w = f2bf(a1.w); w[1] = o;
            o.x = f2bf(a2.x); o.y = f2bf(a2.y); o.z = f2bf(a2.z); o.w = f2bf(a2.w); w[2] = o;
            o.x = f2bf(a3.x); o.y = f2bf(a3.y); o.z = f2bf(a3.z); o.w = f2bf(a3.w); w[3] = o;
#pragma unroll
            for (int p8 = 0; p8 < 8; ++p8) {
                int col = p8 * 32 + colq;
                *(ushort4*)&EDs[nxt][col * ED_LD + seg * 4] = e[p8];
            }
        }
        __syncthreads();
        cur ^= 1;
    }

#pragma unroll
    for (int fi = 0; fi < 4; ++fi)
#pragma unroll
        for (int fj = 0; fj < 4; ++fj) {
            int n_base = n0 + wvn * 64 + fi * 16 + g * 4;
            int m = wvc * 64 + fj * 16 + m16;
            bf16x4 o;
#pragma unroll
            for (int r = 0; r < 4; ++r) {
                float w = acc[fi][fj][r];
                float v = acc[fi][fj + 4][r];
                float cc = C[(size_t)(n_base + r) * M_SZ + m];
                o[r] = (short)f2bf(cc * (1.0f - w) + v);
            }
            *(bf16x4*)&NCt[(size_t)m * N_SZ + n_base] = o;
        }
}

// =======================  PASS 2  (R3 body; atomic-free epilogue) ==============
// part[ks][b][m] = sum over k-slice ks; k0=(bid>>3)*1024, b0=(bid&7)*128.
#define L2_LD 40

__global__ __launch_bounds__(256, 2) void k_pass2(
    const float* __restrict__ A,
    const unsigned short* __restrict__ NCt,  // [M][N]
    float* __restrict__ part)                // [64][B][M] f32 partials
{
    __shared__ __align__(16) unsigned short As2[2][128 * L2_LD];
    __shared__ __align__(16) unsigned short NCs[2][128 * L2_LD];
    const int t = threadIdx.x;
    const int lane = t & 63;
    const int wv = t >> 6;
    const int wvb = wv >> 1, wvm = wv & 1;
    const int g = lane >> 4;
    const int m16 = lane & 15;
    const int b0 = (blockIdx.x & 7) * 128;
    const int ks = blockIdx.x >> 3;
    const int k0 = ks << 10;

    const int row = t >> 1, half = t & 1;

    f32x4 acc[4][4];
#pragma unroll
    for (int i = 0; i < 4; ++i)
#pragma unroll
        for (int j = 0; j < 4; ++j) acc[i][j] = (f32x4){0.f, 0.f, 0.f, 0.f};

    {
        const float* p = A + (size_t)(b0 + row) * N_SZ + k0 + half * 16;
        float4 a0 = ((const float4*)p)[0], a1 = ((const float4*)p)[1];
        float4 a2 = ((const float4*)p)[2], a3 = ((const float4*)p)[3];
        ushort4* w = (ushort4*)&As2[0][row * L2_LD + half * 16];
        ushort4 o;
        o.x = f2bf(a0.x); o.y = f2bf(a0.y); o.z = f2bf(a0.z); o.w = f2bf(a0.w); w[0] = o;
        o.x = f2bf(a1.x); o.y = f2bf(a1.y); o.z = f2bf(a1.z); o.w = f2bf(a1.w); w[1] = o;
        o.x = f2bf(a2.x); o.y = f2bf(a2.y); o.z = f2bf(a2.z); o.w = f2bf(a2.w); w[2] = o;
        o.x = f2bf(a3.x); o.y = f2bf(a3.y); o.z = f2bf(a3.z); o.w = f2bf(a3.w); w[3] = o;
        const uint4* pn = (const uint4*)(NCt + (size_t)row * N_SZ + k0 + half * 16);
        uint4 n0v = pn[0], n1v = pn[1];
        uint4* wn = (uint4*)&NCs[0][row * L2_LD + half * 16];
        wn[0] = n0v; wn[1] = n1v;
    }
    __syncthreads();

    int cur = 0;
    for (int kk = 0; kk < 1024; kk += 32) {
        const bool last = (kk + 32 >= 1024);
        const int nkk = last ? 0 : kk + 32;

        const float* p = A + (size_t)(b0 + row) * N_SZ + k0 + nkk + half * 16;
        float4 a0 = ((const float4*)p)[0], a1 = ((const float4*)p)[1];
        float4 a2 = ((const float4*)p)[2], a3 = ((const float4*)p)[3];
        const uint4* pn = (const uint4*)(NCt + (size_t)row * N_SZ + k0 + nkk + half * 16);
        uint4 n0v = pn[0], n1v = pn[1];

        bf16x8 af[4];
#pragma unroll
        for (int fi = 0; fi < 4; ++fi)
            af[fi] = *(const bf16x8*)&As2[cur][(wvb * 64 + fi * 16 + m16) * L2_LD + g * 8];
        bf16x8 bfr[4];
#pragma unroll
        for (int fj = 0; fj < 4; ++fj)
            bfr[fj] = *(const bf16x8*)&NCs[cur][(wvm * 64 + fj * 16 + m16) * L2_LD + g * 8];

#pragma unroll
        for (int fi = 0; fi < 4; ++fi)
#pragma unroll
            for (int fj = 0; fj < 4; ++fj)
                acc[fi][fj] = __builtin_amdgcn_mfma_f32_16x16x32_bf16(af[fi], bfr[fj], acc[fi][fj], 0, 0, 0);

        if (!last) {
            const int nxt = cur ^ 1;
            ushort4* w = (ushort4*)&As2[nxt][row * L2_LD + half * 16];
            ushort4 o;
            o.x = f2bf(a0.x); o.y = f2bf(a0.y); o.z = f2bf(a0.z); o.w = f2bf(a0.w); w[0] = o;
            o.x = f2bf(a1.x); o.y = f2bf(a1.y); o.z = f2bf(a1.z); o.w = f2bf(a1.w); w[1] = o;
            o.x = f2bf(a2.x); o.y = f2bf(a2.y); o.z = f2bf(a2.z); o.w = f2bf(a2.w); w[2] = o;
            o.x = f2bf(a3.x); o.y = f2bf(a3.y); o.z = f2bf(a3.z); o.w = f2bf(a3.w); w[3] = o;
            uint4* wn = (uint4*)&NCs[nxt][row * L2_LD + half * 16];
            wn[0] = n0v; wn[1] = n1v;
        }
        __syncthreads();
        cur ^= 1;
    }

    // plain coalesced stores to partials (no atomics)
    float* pp = part + (size_t)ks * (B_SZ * M_SZ);
#pragma unroll
    for (int fi = 0; fi < 4; ++fi)
#pragma unroll
        for (int fj = 0; fj < 4; ++fj)
#pragma unroll
            for (int r = 0; r < 4; ++r) {
                int b = b0 + wvb * 64 + fi * 16 + g * 4 + r;
                int m = wvm * 64 + fj * 16 + m16;
                pp[(size_t)b * M_SZ + m] = acc[fi][fj][r];
            }
}

// ---- reduce: out[b][m] = sum_{s<64} part[s][b][m].  128 blocks x 256 thr x float4.
__global__ __launch_bounds__(256) void k_reduce(const float* __restrict__ part,
                                                float* __restrict__ out) {
    const int idx4 = blockIdx.x * 256 + threadIdx.x;   // 0..32767
    const float* p = part + (size_t)idx4 * 4;
    f32x4 s0 = {0.f,0.f,0.f,0.f}, s1 = s0, s2 = s0, s3 = s0;
#pragma unroll
    for (int s = 0; s < 64; s += 4) {
        f32x4 v0 = *(const f32x4*)(p + (size_t)(s + 0) * (B_SZ * M_SZ));
        f32x4 v1 = *(const f32x4*)(p + (size_t)(s + 1) * (B_SZ * M_SZ));
        f32x4 v2 = *(const f32x4*)(p + (size_t)(s + 2) * (B_SZ * M_SZ));
        f32x4 v3 = *(const f32x4*)(p + (size_t)(s + 3) * (B_SZ * M_SZ));
        s0 += v0; s1 += v1; s2 += v2; s3 += v3;
    }
    f32x4 r = (s0 + s1) + (s2 + s3);
    *(f32x4*)(out + (size_t)idx4 * 4) = r;
}

extern "C" void kernel_launch(void* const* d_in, const int* in_sizes, int n_in,
                              void* d_out, int out_size, void* d_ws, size_t ws_size,
                              hipStream_t stream) {
    const float* A  = (const float*)d_in[0];   // address [B,N]
    const float* E  = (const float*)d_in[1];   // erase   [B,M]
    const float* Dd = (const float*)d_in[2];   // add     [B,M]
    const float* C  = (const float*)d_in[3];   // content [N,M]
    float* out = (float*)d_out;

    unsigned short* NCt = (unsigned short*)d_ws;                                      // 16 MB [M][N]
    unsigned short* EDt = (unsigned short*)((char*)d_ws + (size_t)M_SZ * N_SZ * 2);   // +512 KB
    float* part = (float*)((char*)d_ws + (size_t)M_SZ * N_SZ * 2 + (size_t)256 * B_SZ * 2); // +32 MB

    k_edt   <<<256, 256, 0, stream>>>(E, Dd, EDt);
    k_pass1 <<<512, 256, 0, stream>>>(A, EDt, C, NCt);
    k_pass2 <<<512, 256, 0, stream>>>(A, NCt, part);
    k_reduce<<<128, 256, 0, stream>>>(part, out);
}

// Round 10
// 151.991 us; speedup vs baseline: 1.4691x; 1.0978x over previous
//
#include <hip/hip_runtime.h>
#include <hip/hip_bf16.h>
#include <stdint.h>

#define B_SZ 1024
#define N_SZ 65536
#define M_SZ 128

typedef short bf16x8 __attribute__((ext_vector_type(8)));
typedef short bf16x4 __attribute__((ext_vector_type(4)));
typedef float f32x4 __attribute__((ext_vector_type(4)));

__device__ __forceinline__ unsigned short f2bf(float f) {
    uint32_t u = __float_as_uint(f);
    uint32_t r = (u + 0x7FFFu + ((u >> 16) & 1u)) >> 16;  // RNE
    return (unsigned short)r;
}

// ---- kernel 0: EDt[c][b] bf16, c<128 -> E[b][c], else D[b][c-128]. [256][1024]
__global__ __launch_bounds__(256) void k_edt(const float* __restrict__ E,
                                             const float* __restrict__ D,
                                             unsigned short* __restrict__ EDt) {
    __shared__ float tile[32][33];
    int bx = blockIdx.x & 31;
    int cy = blockIdx.x >> 5;
    int b0 = bx * 32, c0 = cy * 32;
    const float* src = (c0 < M_SZ) ? E : D;
    int cs0 = c0 & (M_SZ - 1);
    int t = threadIdx.x;
    int i = t >> 3, j = (t & 7) * 4;
    const float* p = src + (size_t)(b0 + i) * M_SZ + cs0 + j;
    float4 v = *(const float4*)p;
    tile[i][j] = v.x; tile[i][j + 1] = v.y; tile[i][j + 2] = v.z; tile[i][j + 3] = v.w;
    __syncthreads();
    int c = t >> 3, b4 = (t & 7) * 4;
    unsigned short* q = EDt + (size_t)(c0 + c) * B_SZ + b0 + b4;
    ushort4 o;
    o.x = f2bf(tile[b4 + 0][c]); o.y = f2bf(tile[b4 + 1][c]);
    o.z = f2bf(tile[b4 + 2][c]); o.w = f2bf(tile[b4 + 3][c]);
    *(ushort4*)q = o;
}

// =======================  PASS 1  =======================
// NCt[m][n] = C[n][m]*(1-W) + V,  (W|V) = A^T @ (E||D)
// block: 128 n x 256 c, K=1024 in 32-chunks.
// A: reg-staged + converted, DEPTH-2 prefetch (slots ra0/ra1), As [32][132] proven.
// ED: global_load_lds width-16, linear dest slot L -> byte L*16; source k-seg
//     pre-swizzled by s(col)=(col>>1)&3; read EDs[col*32 + ((g^s)<<3)] (2-way, free).
#define AS_LD 132

__global__ __launch_bounds__(256, 2) void k_pass1(
    const float* __restrict__ A,            // [B][N]
    const unsigned short* __restrict__ EDt, // [256][B] bf16
    const float* __restrict__ C,            // [N][M]
    unsigned short* __restrict__ NCt)       // [M][N] bf16 out (transposed)
{
    __shared__ __align__(16) unsigned short As[2][32 * AS_LD];
    __shared__ __align__(16) unsigned short EDs[2][256 * 32];
    const int t = threadIdx.x;
    const int lane = t & 63;
    const int wv = t >> 6;
    const int wvn = wv >> 1, wvc = wv & 1;
    const int g = lane >> 4;
    const int m16 = lane & 15;
    const int n0 = blockIdx.x * 128;

    const int kb = t >> 3;          // A staging: b-row within chunk 0..31
    const int cA = (t & 7) * 16;    // A staging: n-col start

    int cb[8];
#pragma unroll
    for (int fj = 0; fj < 4; ++fj) { cb[fj] = wvc * 4 + fj; cb[fj + 4] = 8 + wvc * 4 + fj; }

    f32x4 acc[4][8];
#pragma unroll
    for (int i = 0; i < 4; ++i)
#pragma unroll
        for (int j = 0; j < 8; ++j) acc[i][j] = (f32x4){0.f, 0.f, 0.f, 0.f};

// ---- helpers ----
#define ED_GLLDS(buf, bkv)                                                          \
    {                                                                               \
        _Pragma("unroll")                                                           \
        for (int i_ = 0; i_ < 4; ++i_) {                                            \
            int L_ = i_ * 256 + t;                                                  \
            int col_ = L_ >> 2;                                                     \
            int ss_ = (L_ & 3) ^ ((col_ >> 1) & 3);                                 \
            const unsigned short* gsrc_ = EDt + (size_t)col_ * B_SZ + (bkv) + ss_ * 8; \
            __builtin_amdgcn_global_load_lds(                                       \
                (const __attribute__((address_space(1))) uint32_t*)(const void*)gsrc_, \
                (__attribute__((address_space(3))) uint32_t*)(void*)&EDs[buf][(i_ * 256 + wv * 64) * 8], \
                16, 0, 0);                                                          \
        }                                                                           \
    }

#define A_LOAD(dst0, dst1, dst2, dst3, bkv)                                         \
    {                                                                               \
        const float* p_ = A + (size_t)((bkv) + kb) * N_SZ + n0 + cA;                \
        dst0 = ((const float4*)p_)[0]; dst1 = ((const float4*)p_)[1];               \
        dst2 = ((const float4*)p_)[2]; dst3 = ((const float4*)p_)[3];               \
    }

#define A_WRITE(buf, s0, s1, s2, s3)                                                \
    {                                                                               \
        ushort4* w_ = (ushort4*)&As[buf][kb * AS_LD + cA];                          \
        ushort4 o_;                                                                 \
        o_.x = f2bf(s0.x); o_.y = f2bf(s0.y); o_.z = f2bf(s0.z); o_.w = f2bf(s0.w); w_[0] = o_; \
        o_.x = f2bf(s1.x); o_.y = f2bf(s1.y); o_.z = f2bf(s1.z); o_.w = f2bf(s1.w); w_[1] = o_; \
        o_.x = f2bf(s2.x); o_.y = f2bf(s2.y); o_.z = f2bf(s2.z); o_.w = f2bf(s2.w); w_[2] = o_; \
        o_.x = f2bf(s3.x); o_.y = f2bf(s3.y); o_.z = f2bf(s3.z); o_.w = f2bf(s3.w); w_[3] = o_; \
    }

#define P1_COMPUTE(buf)                                                             \
    {                                                                               \
        bf16x8 af_[4];                                                              \
        _Pragma("unroll")                                                           \
        for (int fi = 0; fi < 4; ++fi) {                                            \
            int nl_ = wvn * 64 + fi * 16 + m16;                                     \
            _Pragma("unroll")                                                       \
            for (int j = 0; j < 8; ++j)                                             \
                af_[fi][j] = (short)As[buf][(g * 8 + j) * AS_LD + nl_];              \
        }                                                                           \
        bf16x8 bfr_[8];                                                             \
        _Pragma("unroll")                                                           \
        for (int fj = 0; fj < 8; ++fj) {                                            \
            int col_ = cb[fj] * 16 + m16;                                           \
            bfr_[fj] = *(const bf16x8*)&EDs[buf][col_ * 32 + ((g ^ ((col_ >> 1) & 3)) << 3)]; \
        }                                                                           \
        _Pragma("unroll")                                                           \
        for (int fj = 0; fj < 8; ++fj)                                              \
            _Pragma("unroll")                                                       \
            for (int fi = 0; fi < 4; ++fi)                                          \
                acc[fi][fj] = __builtin_amdgcn_mfma_f32_16x16x32_bf16(af_[fi], bfr_[fj], acc[fi][fj], 0, 0, 0); \
    }

    float4 ra0_0, ra0_1, ra0_2, ra0_3;   // slot 0 (even chunks)
    float4 ra1_0, ra1_1, ra1_2, ra1_3;   // slot 1 (odd chunks)

    // ---- prologue: chunk0 -> buf0 (A direct, ED gl_lds); chunk1 -> ra1
    A_LOAD(ra0_0, ra0_1, ra0_2, ra0_3, 0)
    ED_GLLDS(0, 0)
    A_WRITE(0, ra0_0, ra0_1, ra0_2, ra0_3)
    A_LOAD(ra1_0, ra1_1, ra1_2, ra1_3, 32)
    __syncthreads();

    for (int c = 0; c < 32; c += 2) {
        // ===== even iter: compute chunk c from buf0 =====
        if (c + 1 < 32) ED_GLLDS(1, (c + 1) * 32)
        if (c + 2 < 32) A_LOAD(ra0_0, ra0_1, ra0_2, ra0_3, (c + 2) * 32)
        P1_COMPUTE(0)
        if (c + 1 < 32) A_WRITE(1, ra1_0, ra1_1, ra1_2, ra1_3)
        __syncthreads();
        // ===== odd iter: compute chunk c+1 from buf1 =====
        if (c + 1 < 32) {
            if (c + 2 < 32) ED_GLLDS(0, (c + 2) * 32)
            if (c + 3 < 32) A_LOAD(ra1_0, ra1_1, ra1_2, ra1_3, (c + 3) * 32)
            P1_COMPUTE(1)
            if (c + 2 < 32) A_WRITE(0, ra0_0, ra0_1, ra0_2, ra0_3)
            __syncthreads();
        }
    }

    // epilogue: D layout col=lane&15, row=(lane>>4)*4+r. NCt[m][n]: n contiguous.
#pragma unroll
    for (int fi = 0; fi < 4; ++fi)
#pragma unroll
        for (int fj = 0; fj < 4; ++fj) {
            int n_base = n0 + wvn * 64 + fi * 16 + g * 4;
            int m = wvc * 64 + fj * 16 + m16;
            bf16x4 o;
#pragma unroll
            for (int r = 0; r < 4; ++r) {
                float w = acc[fi][fj][r];
                float v = acc[fi][fj + 4][r];
                float cc = C[(size_t)(n_base + r) * M_SZ + m];
                o[r] = (short)f2bf(cc * (1.0f - w) + v);
            }
            *(bf16x4*)&NCt[(size_t)m * N_SZ + n_base] = o;
        }
}

// =======================  PASS 2  (verbatim R9 — proven) ==============
#define L2_LD 40

__global__ __launch_bounds__(256, 2) void k_pass2(
    const float* __restrict__ A,
    const unsigned short* __restrict__ NCt,  // [M][N]
    float* __restrict__ part)                // [64][B][M] f32 partials
{
    __shared__ __align__(16) unsigned short As2[2][128 * L2_LD];
    __shared__ __align__(16) unsigned short NCs[2][128 * L2_LD];
    const int t = threadIdx.x;
    const int lane = t & 63;
    const int wv = t >> 6;
    const int wvb = wv >> 1, wvm = wv & 1;
    const int g = lane >> 4;
    const int m16 = lane & 15;
    const int b0 = (blockIdx.x & 7) * 128;
    const int ks = blockIdx.x >> 3;
    const int k0 = ks << 10;

    const int row = t >> 1, half = t & 1;

    f32x4 acc[4][4];
#pragma unroll
    for (int i = 0; i < 4; ++i)
#pragma unroll
        for (int j = 0; j < 4; ++j) acc[i][j] = (f32x4){0.f, 0.f, 0.f, 0.f};

    {
        const float* p = A + (size_t)(b0 + row) * N_SZ + k0 + half * 16;
        float4 a0 = ((const float4*)p)[0], a1 = ((const float4*)p)[1];
        float4 a2 = ((const float4*)p)[2], a3 = ((const float4*)p)[3];
        ushort4* w = (ushort4*)&As2[0][row * L2_LD + half * 16];
        ushort4 o;
        o.x = f2bf(a0.x); o.y = f2bf(a0.y); o.z = f2bf(a0.z); o.w = f2bf(a0.w); w[0] = o;
        o.x = f2bf(a1.x); o.y = f2bf(a1.y); o.z = f2bf(a1.z); o.w = f2bf(a1.w); w[1] = o;
        o.x = f2bf(a2.x); o.y = f2bf(a2.y); o.z = f2bf(a2.z); o.w = f2bf(a2.w); w[2] = o;
        o.x = f2bf(a3.x); o.y = f2bf(a3.y); o.z = f2bf(a3.z); o.w = f2bf(a3.w); w[3] = o;
        const uint4* pn = (const uint4*)(NCt + (size_t)row * N_SZ + k0 + half * 16);
        uint4 n0v = pn[0], n1v = pn[1];
        uint4* wn = (uint4*)&NCs[0][row * L2_LD + half * 16];
        wn[0] = n0v; wn[1] = n1v;
    }
    __syncthreads();

    int cur = 0;
    for (int kk = 0; kk < 1024; kk += 32) {
        const bool last = (kk + 32 >= 1024);
        const int nkk = last ? 0 : kk + 32;

        const float* p = A + (size_t)(b0 + row) * N_SZ + k0 + nkk + half * 16;
        float4 a0 = ((const float4*)p)[0], a1 = ((const float4*)p)[1];
        float4 a2 = ((const float4*)p)[2], a3 = ((const float4*)p)[3];
        const uint4* pn = (const uint4*)(NCt + (size_t)row * N_SZ + k0 + nkk + half * 16);
        uint4 n0v = pn[0], n1v = pn[1];

        bf16x8 af[4];
#pragma unroll
        for (int fi = 0; fi < 4; ++fi)
            af[fi] = *(const bf16x8*)&As2[cur][(wvb * 64 + fi * 16 + m16) * L2_LD + g * 8];
        bf16x8 bfr[4];
#pragma unroll
        for (int fj = 0; fj < 4; ++fj)
            bfr[fj] = *(const bf16x8*)&NCs[cur][(wvm * 64 + fj * 16 + m16) * L2_LD + g * 8];

#pragma unroll
        for (int fi = 0; fi < 4; ++fi)
#pragma unroll
            for (int fj = 0; fj < 4; ++fj)
                acc[fi][fj] = __builtin_amdgcn_mfma_f32_16x16x32_bf16(af[fi], bfr[fj], acc[fi][fj], 0, 0, 0);

        if (!last) {
            const int nxt = cur ^ 1;
            ushort4* w = (ushort4*)&As2[nxt][row * L2_LD + half * 16];
            ushort4 o;
            o.x = f2bf(a0.x); o.y = f2bf(a0.y); o.z = f2bf(a0.z); o.w = f2bf(a0.w); w[0] = o;
            o.x = f2bf(a1.x); o.y = f2bf(a1.y); o.z = f2bf(a1.z); o.w = f2bf(a1.w); w[1] = o;
            o.x = f2bf(a2.x); o.y = f2bf(a2.y); o.z = f2bf(a2.z); o.w = f2bf(a2.w); w[2] = o;
            o.x = f2bf(a3.x); o.y = f2bf(a3.y); o.z = f2bf(a3.z); o.w = f2bf(a3.w); w[3] = o;
            uint4* wn = (uint4*)&NCs[nxt][row * L2_LD + half * 16];
            wn[0] = n0v; wn[1] = n1v;
        }
        __syncthreads();
        cur ^= 1;
    }

    float* pp = part + (size_t)ks * (B_SZ * M_SZ);
#pragma unroll
    for (int fi = 0; fi < 4; ++fi)
#pragma unroll
        for (int fj = 0; fj < 4; ++fj)
#pragma unroll
            for (int r = 0; r < 4; ++r) {
                int b = b0 + wvb * 64 + fi * 16 + g * 4 + r;
                int m = wvm * 64 + fj * 16 + m16;
                pp[(size_t)b * M_SZ + m] = acc[fi][fj][r];
            }
}

// ---- reduce: out[b][m] = sum_{s<64} part[s][b][m].  128 blocks x 256 thr x float4.
__global__ __launch_bounds__(256) void k_reduce(const float* __restrict__ part,
                                                float* __restrict__ out) {
    const int idx4 = blockIdx.x * 256 + threadIdx.x;   // 0..32767
    const float* p = part + (size_t)idx4 * 4;
    f32x4 s0 = {0.f,0.f,0.f,0.f}, s1 = s0, s2 = s0, s3 = s0;
#pragma unroll
    for (int s = 0; s < 64; s += 4) {
        f32x4 v0 = *(const f32x4*)(p + (size_t)(s + 0) * (B_SZ * M_SZ));
        f32x4 v1 = *(const f32x4*)(p + (size_t)(s + 1) * (B_SZ * M_SZ));
        f32x4 v2 = *(const f32x4*)(p + (size_t)(s + 2) * (B_SZ * M_SZ));
        f32x4 v3 = *(const f32x4*)(p + (size_t)(s + 3) * (B_SZ * M_SZ));
        s0 += v0; s1 += v1; s2 += v2; s3 += v3;
    }
    f32x4 r = (s0 + s1) + (s2 + s3);
    *(f32x4*)(out + (size_t)idx4 * 4) = r;
}

extern "C" void kernel_launch(void* const* d_in, const int* in_sizes, int n_in,
                              void* d_out, int out_size, void* d_ws, size_t ws_size,
                              hipStream_t stream) {
    const float* A  = (const float*)d_in[0];   // address [B,N]
    const float* E  = (const float*)d_in[1];   // erase   [B,M]
    const float* Dd = (const float*)d_in[2];   // add     [B,M]
    const float* C  = (const float*)d_in[3];   // content [N,M]
    float* out = (float*)d_out;

    unsigned short* NCt = (unsigned short*)d_ws;                                      // 16 MB [M][N]
    unsigned short* EDt = (unsigned short*)((char*)d_ws + (size_t)M_SZ * N_SZ * 2);   // +512 KB
    float* part = (float*)((char*)d_ws + (size_t)M_SZ * N_SZ * 2 + (size_t)256 * B_SZ * 2); // +32 MB

    k_edt   <<<256, 256, 0, stream>>>(E, Dd, EDt);
    k_pass1 <<<512, 256, 0, stream>>>(A, EDt, C, NCt);
    k_pass2 <<<512, 256, 0, stream>>>(A, NCt, part);
    k_reduce<<<128, 256, 0, stream>>>(part, out);
}

// Round 11
// 151.423 us; speedup vs baseline: 1.4746x; 1.0038x over previous
//
#include <hip/hip_runtime.h>
#include <hip/hip_bf16.h>
#include <stdint.h>

#define B_SZ 1024
#define N_SZ 65536
#define M_SZ 128

typedef short bf16x8 __attribute__((ext_vector_type(8)));
typedef short bf16x4 __attribute__((ext_vector_type(4)));
typedef float f32x4 __attribute__((ext_vector_type(4)));

__device__ __forceinline__ unsigned short f2bf(float f) {
    uint32_t u = __float_as_uint(f);
    uint32_t r = (u + 0x7FFFu + ((u >> 16) & 1u)) >> 16;  // RNE
    return (unsigned short)r;
}

// ---- kernel 0: EDt[c][b] bf16, c<128 -> E[b][c], else D[b][c-128]. [256][1024]
__global__ __launch_bounds__(256) void k_edt(const float* __restrict__ E,
                                             const float* __restrict__ D,
                                             unsigned short* __restrict__ EDt) {
    __shared__ float tile[32][33];
    int bx = blockIdx.x & 31;
    int cy = blockIdx.x >> 5;
    int b0 = bx * 32, c0 = cy * 32;
    const float* src = (c0 < M_SZ) ? E : D;
    int cs0 = c0 & (M_SZ - 1);
    int t = threadIdx.x;
    int i = t >> 3, j = (t & 7) * 4;
    const float* p = src + (size_t)(b0 + i) * M_SZ + cs0 + j;
    float4 v = *(const float4*)p;
    tile[i][j] = v.x; tile[i][j + 1] = v.y; tile[i][j + 2] = v.z; tile[i][j + 3] = v.w;
    __syncthreads();
    int c = t >> 3, b4 = (t & 7) * 4;
    unsigned short* q = EDt + (size_t)(c0 + c) * B_SZ + b0 + b4;
    ushort4 o;
    o.x = f2bf(tile[b4 + 0][c]); o.y = f2bf(tile[b4 + 1][c]);
    o.z = f2bf(tile[b4 + 2][c]); o.w = f2bf(tile[b4 + 3][c]);
    *(ushort4*)q = o;
}

// =======================  PASS 1  (verbatim R10 — proven 152) =======================
#define AS_LD 132

__global__ __launch_bounds__(256, 2) void k_pass1(
    const float* __restrict__ A,            // [B][N]
    const unsigned short* __restrict__ EDt, // [256][B] bf16
    const float* __restrict__ C,            // [N][M]
    unsigned short* __restrict__ NCt)       // [M][N] bf16 out (transposed)
{
    __shared__ __align__(16) unsigned short As[2][32 * AS_LD];
    __shared__ __align__(16) unsigned short EDs[2][256 * 32];
    const int t = threadIdx.x;
    const int lane = t & 63;
    const int wv = t >> 6;
    const int wvn = wv >> 1, wvc = wv & 1;
    const int g = lane >> 4;
    const int m16 = lane & 15;
    const int n0 = blockIdx.x * 128;

    const int kb = t >> 3;
    const int cA = (t & 7) * 16;

    int cb[8];
#pragma unroll
    for (int fj = 0; fj < 4; ++fj) { cb[fj] = wvc * 4 + fj; cb[fj + 4] = 8 + wvc * 4 + fj; }

    f32x4 acc[4][8];
#pragma unroll
    for (int i = 0; i < 4; ++i)
#pragma unroll
        for (int j = 0; j < 8; ++j) acc[i][j] = (f32x4){0.f, 0.f, 0.f, 0.f};

#define ED_GLLDS(buf, bkv)                                                          \
    {                                                                               \
        _Pragma("unroll")                                                           \
        for (int i_ = 0; i_ < 4; ++i_) {                                            \
            int L_ = i_ * 256 + t;                                                  \
            int col_ = L_ >> 2;                                                     \
            int ss_ = (L_ & 3) ^ ((col_ >> 1) & 3);                                 \
            const unsigned short* gsrc_ = EDt + (size_t)col_ * B_SZ + (bkv) + ss_ * 8; \
            __builtin_amdgcn_global_load_lds(                                       \
                (const __attribute__((address_space(1))) uint32_t*)(const void*)gsrc_, \
                (__attribute__((address_space(3))) uint32_t*)(void*)&EDs[buf][(i_ * 256 + wv * 64) * 8], \
                16, 0, 0);                                                          \
        }                                                                           \
    }

#define A_LOAD(dst0, dst1, dst2, dst3, bkv)                                         \
    {                                                                               \
        const float* p_ = A + (size_t)((bkv) + kb) * N_SZ + n0 + cA;                \
        dst0 = ((const float4*)p_)[0]; dst1 = ((const float4*)p_)[1];               \
        dst2 = ((const float4*)p_)[2]; dst3 = ((const float4*)p_)[3];               \
    }

#define A_WRITE(buf, s0, s1, s2, s3)                                                \
    {                                                                               \
        ushort4* w_ = (ushort4*)&As[buf][kb * AS_LD + cA];                          \
        ushort4 o_;                                                                 \
        o_.x = f2bf(s0.x); o_.y = f2bf(s0.y); o_.z = f2bf(s0.z); o_.w = f2bf(s0.w); w_[0] = o_; \
        o_.x = f2bf(s1.x); o_.y = f2bf(s1.y); o_.z = f2bf(s1.z); o_.w = f2bf(s1.w); w_[1] = o_; \
        o_.x = f2bf(s2.x); o_.y = f2bf(s2.y); o_.z = f2bf(s2.z); o_.w = f2bf(s2.w); w_[2] = o_; \
        o_.x = f2bf(s3.x); o_.y = f2bf(s3.y); o_.z = f2bf(s3.z); o_.w = f2bf(s3.w); w_[3] = o_; \
    }

#define P1_COMPUTE(buf)                                                             \
    {                                                                               \
        bf16x8 af_[4];                                                              \
        _Pragma("unroll")                                                           \
        for (int fi = 0; fi < 4; ++fi) {                                            \
            int nl_ = wvn * 64 + fi * 16 + m16;                                     \
            _Pragma("unroll")                                                       \
            for (int j = 0; j < 8; ++j)                                             \
                af_[fi][j] = (short)As[buf][(g * 8 + j) * AS_LD + nl_];              \
        }                                                                           \
        bf16x8 bfr_[8];                                                             \
        _Pragma("unroll")                                                           \
        for (int fj = 0; fj < 8; ++fj) {                                            \
            int col_ = cb[fj] * 16 + m16;                                           \
            bfr_[fj] = *(const bf16x8*)&EDs[buf][col_ * 32 + ((g ^ ((col_ >> 1) & 3)) << 3)]; \
        }                                                                           \
        _Pragma("unroll")                                                           \
        for (int fj = 0; fj < 8; ++fj)                                              \
            _Pragma("unroll")                                                       \
            for (int fi = 0; fi < 4; ++fi)                                          \
                acc[fi][fj] = __builtin_amdgcn_mfma_f32_16x16x32_bf16(af_[fi], bfr_[fj], acc[fi][fj], 0, 0, 0); \
    }

    float4 ra0_0, ra0_1, ra0_2, ra0_3;
    float4 ra1_0, ra1_1, ra1_2, ra1_3;

    A_LOAD(ra0_0, ra0_1, ra0_2, ra0_3, 0)
    ED_GLLDS(0, 0)
    A_WRITE(0, ra0_0, ra0_1, ra0_2, ra0_3)
    A_LOAD(ra1_0, ra1_1, ra1_2, ra1_3, 32)
    __syncthreads();

    for (int c = 0; c < 32; c += 2) {
        if (c + 1 < 32) ED_GLLDS(1, (c + 1) * 32)
        if (c + 2 < 32) A_LOAD(ra0_0, ra0_1, ra0_2, ra0_3, (c + 2) * 32)
        P1_COMPUTE(0)
        if (c + 1 < 32) A_WRITE(1, ra1_0, ra1_1, ra1_2, ra1_3)
        __syncthreads();
        if (c + 1 < 32) {
            if (c + 2 < 32) ED_GLLDS(0, (c + 2) * 32)
            if (c + 3 < 32) A_LOAD(ra1_0, ra1_1, ra1_2, ra1_3, (c + 3) * 32)
            P1_COMPUTE(1)
            if (c + 2 < 32) A_WRITE(0, ra0_0, ra0_1, ra0_2, ra0_3)
            __syncthreads();
        }
    }

#pragma unroll
    for (int fi = 0; fi < 4; ++fi)
#pragma unroll
        for (int fj = 0; fj < 4; ++fj) {
            int n_base = n0 + wvn * 64 + fi * 16 + g * 4;
            int m = wvc * 64 + fj * 16 + m16;
            bf16x4 o;
#pragma unroll
            for (int r = 0; r < 4; ++r) {
                float w = acc[fi][fj][r];
                float v = acc[fi][fj + 4][r];
                float cc = C[(size_t)(n_base + r) * M_SZ + m];
                o[r] = (short)f2bf(cc * (1.0f - w) + v);
            }
            *(bf16x4*)&NCt[(size_t)m * N_SZ + n_base] = o;
        }
}

// =======================  PASS 2  =======================
// part[ks][b][m]; R9 geometry (64 ks x 8 bg). Upgrades (mirror of proven pass1):
//   NCt staging -> global_load_lds w16, linear dest, src k-seg swz (L&3)^((row>>1)&3),
//                  read NCs[row*32 + ((g^((row>>1)&3))<<3)]  (2-way, free);
//   A staging   -> depth-2 named-slot prefetch.
#define L2_LD 40

__global__ __launch_bounds__(256, 2) void k_pass2(
    const float* __restrict__ A,
    const unsigned short* __restrict__ NCt,  // [M][N]
    float* __restrict__ part)                // [64][B][M] f32 partials
{
    __shared__ __align__(16) unsigned short As2[2][128 * L2_LD];
    __shared__ __align__(16) unsigned short NCs[2][128 * 32];
    const int t = threadIdx.x;
    const int lane = t & 63;
    const int wv = t >> 6;
    const int wvb = wv >> 1, wvm = wv & 1;
    const int g = lane >> 4;
    const int m16 = lane & 15;
    const int b0 = (blockIdx.x & 7) * 128;
    const int ks = blockIdx.x >> 3;
    const int k0 = ks << 10;

    const int row = t >> 1, half = t & 1;

    f32x4 acc[4][4];
#pragma unroll
    for (int i = 0; i < 4; ++i)
#pragma unroll
        for (int j = 0; j < 4; ++j) acc[i][j] = (f32x4){0.f, 0.f, 0.f, 0.f};

#define NC_GLLDS(buf, kkv)                                                          \
    {                                                                               \
        _Pragma("unroll")                                                           \
        for (int i_ = 0; i_ < 2; ++i_) {                                            \
            int L_ = i_ * 256 + t;                                                  \
            int row_ = L_ >> 2;                                                     \
            int ss_ = (L_ & 3) ^ ((row_ >> 1) & 3);                                 \
            const unsigned short* gsrc_ = NCt + (size_t)row_ * N_SZ + k0 + (kkv) + ss_ * 8; \
            __builtin_amdgcn_global_load_lds(                                       \
                (const __attribute__((address_space(1))) uint32_t*)(const void*)gsrc_, \
                (__attribute__((address_space(3))) uint32_t*)(void*)&NCs[buf][L_ * 8], \
                16, 0, 0);                                                          \
        }                                                                           \
    }

#define A2_LOAD(dst0, dst1, dst2, dst3, kkv)                                        \
    {                                                                               \
        const float* p_ = A + (size_t)(b0 + row) * N_SZ + k0 + (kkv) + half * 16;   \
        dst0 = ((const float4*)p_)[0]; dst1 = ((const float4*)p_)[1];               \
        dst2 = ((const float4*)p_)[2]; dst3 = ((const float4*)p_)[3];               \
    }

#define A2_WRITE(buf, s0, s1, s2, s3)                                               \
    {                                                                               \
        ushort4* w_ = (ushort4*)&As2[buf][row * L2_LD + half * 16];                 \
        ushort4 o_;                                                                 \
        o_.x = f2bf(s0.x); o_.y = f2bf(s0.y); o_.z = f2bf(s0.z); o_.w = f2bf(s0.w); w_[0] = o_; \
        o_.x = f2bf(s1.x); o_.y = f2bf(s1.y); o_.z = f2bf(s1.z); o_.w = f2bf(s1.w); w_[1] = o_; \
        o_.x = f2bf(s2.x); o_.y = f2bf(s2.y); o_.z = f2bf(s2.z); o_.w = f2bf(s2.w); w_[2] = o_; \
        o_.x = f2bf(s3.x); o_.y = f2bf(s3.y); o_.z = f2bf(s3.z); o_.w = f2bf(s3.w); w_[3] = o_; \
    }

#define P2_COMPUTE(buf)                                                             \
    {                                                                               \
        bf16x8 af_[4];                                                              \
        _Pragma("unroll")                                                           \
        for (int fi = 0; fi < 4; ++fi)                                              \
            af_[fi] = *(const bf16x8*)&As2[buf][(wvb * 64 + fi * 16 + m16) * L2_LD + g * 8]; \
        bf16x8 bfr_[4];                                                             \
        _Pragma("unroll")                                                           \
        for (int fj = 0; fj < 4; ++fj) {                                            \
            int row_ = wvm * 64 + fj * 16 + m16;                                    \
            bfr_[fj] = *(const bf16x8*)&NCs[buf][row_ * 32 + ((g ^ ((row_ >> 1) & 3)) << 3)]; \
        }                                                                           \
        _Pragma("unroll")                                                           \
        for (int fi = 0; fi < 4; ++fi)                                              \
            _Pragma("unroll")                                                       \
            for (int fj = 0; fj < 4; ++fj)                                          \
                acc[fi][fj] = __builtin_amdgcn_mfma_f32_16x16x32_bf16(af_[fi], bfr_[fj], acc[fi][fj], 0, 0, 0); \
    }

    float4 rb0_0, rb0_1, rb0_2, rb0_3;
    float4 rb1_0, rb1_1, rb1_2, rb1_3;

    A2_LOAD(rb0_0, rb0_1, rb0_2, rb0_3, 0)
    NC_GLLDS(0, 0)
    A2_WRITE(0, rb0_0, rb0_1, rb0_2, rb0_3)
    A2_LOAD(rb1_0, rb1_1, rb1_2, rb1_3, 32)
    __syncthreads();

    for (int c = 0; c < 32; c += 2) {
        if (c + 1 < 32) NC_GLLDS(1, (c + 1) * 32)
        if (c + 2 < 32) A2_LOAD(rb0_0, rb0_1, rb0_2, rb0_3, (c + 2) * 32)
        P2_COMPUTE(0)
        if (c + 1 < 32) A2_WRITE(1, rb1_0, rb1_1, rb1_2, rb1_3)
        __syncthreads();
        if (c + 1 < 32) {
            if (c + 2 < 32) NC_GLLDS(0, (c + 2) * 32)
            if (c + 3 < 32) A2_LOAD(rb1_0, rb1_1, rb1_2, rb1_3, (c + 3) * 32)
            P2_COMPUTE(1)
            if (c + 2 < 32) A2_WRITE(0, rb0_0, rb0_1, rb0_2, rb0_3)
            __syncthreads();
        }
    }

    float* pp = part + (size_t)ks * (B_SZ * M_SZ);
#pragma unroll
    for (int fi = 0; fi < 4; ++fi)
#pragma unroll
        for (int fj = 0; fj < 4; ++fj)
#pragma unroll
            for (int r = 0; r < 4; ++r) {
                int b = b0 + wvb * 64 + fi * 16 + g * 4 + r;
                int m = wvm * 64 + fj * 16 + m16;
                pp[(size_t)b * M_SZ + m] = acc[fi][fj][r];
            }
}

// ---- reduce: out[b][m] = sum_{s<64} part[s][b][m].  128 blocks x 256 thr x float4.
__global__ __launch_bounds__(256) void k_reduce(const float* __restrict__ part,
                                                float* __restrict__ out) {
    const int idx4 = blockIdx.x * 256 + threadIdx.x;   // 0..32767
    const float* p = part + (size_t)idx4 * 4;
    f32x4 s0 = {0.f,0.f,0.f,0.f}, s1 = s0, s2 = s0, s3 = s0;
#pragma unroll
    for (int s = 0; s < 64; s += 4) {
        f32x4 v0 = *(const f32x4*)(p + (size_t)(s + 0) * (B_SZ * M_SZ));
        f32x4 v1 = *(const f32x4*)(p + (size_t)(s + 1) * (B_SZ * M_SZ));
        f32x4 v2 = *(const f32x4*)(p + (size_t)(s + 2) * (B_SZ * M_SZ));
        f32x4 v3 = *(const f32x4*)(p + (size_t)(s + 3) * (B_SZ * M_SZ));
        s0 += v0; s1 += v1; s2 += v2; s3 += v3;
    }
    f32x4 r = (s0 + s1) + (s2 + s3);
    *(f32x4*)(out + (size_t)idx4 * 4) = r;
}

extern "C" void kernel_launch(void* const* d_in, const int* in_sizes, int n_in,
                              void* d_out, int out_size, void* d_ws, size_t ws_size,
                              hipStream_t stream) {
    const float* A  = (const float*)d_in[0];   // address [B,N]
    const float* E  = (const float*)d_in[1];   // erase   [B,M]
    const float* Dd = (const float*)d_in[2];   // add     [B,M]
    const float* C  = (const float*)d_in[3];   // content [N,M]
    float* out = (float*)d_out;

    unsigned short* NCt = (unsigned short*)d_ws;                                      // 16 MB [M][N]
    unsigned short* EDt = (unsigned short*)((char*)d_ws + (size_t)M_SZ * N_SZ * 2);   // +512 KB
    float* part = (float*)((char*)d_ws + (size_t)M_SZ * N_SZ * 2 + (size_t)256 * B_SZ * 2); // +32 MB

    k_edt   <<<256, 256, 0, stream>>>(E, Dd, EDt);
    k_pass1 <<<512, 256, 0, stream>>>(A, EDt, C, NCt);
    k_pass2 <<<512, 256, 0, stream>>>(A, NCt, part);
    k_reduce<<<128, 256, 0, stream>>>(part, out);
}